// Round 6
// baseline (132.742 us; speedup 1.0000x reference)
//
#include <hip/hip_runtime.h>

// B=8, H=W=128, Cin=128, Cout=256, 3x3 stride2 pad1 -> OH=OW=64.
// Implicit GEMM: M=32768, N=256, K=1152 (9 taps x 128).
// d_out (f32): out_feats[32768*256] | out_coords[32768*3] | alpha[1]
// R13: R12 fused-band structure, but 16 WAVES (1024 thr) per block instead of 8.
//      Wave tile 32m x 64n (acc 2x v16f). 4 waves/SIMD doubles latency hiding in
//      all 3 serialized phases (band-load, tap loop, epilogue) -- R12 counters
//      showed Occupancy 19%, MfmaUtil 16%: phase latency, not pipes, binds.
//      B staging 2 gload_lds/wave/tap, counted vmcnt(2). Band load unroll x4,
//      stageB(0) overlapped with band phase.

#define OUT_FEATS_ELEMS (32768 * 256)
#define OUT_COORDS_OFF  OUT_FEATS_ELEMS
#define ALPHA_OFF       (OUT_FEATS_ELEMS + 32768 * 3)

#define BW_BYTES   (18 * 16384)

typedef float v16f __attribute__((ext_vector_type(16)));

__device__ __forceinline__ unsigned pk4fp8(float a, float b, float c, float d) {
    unsigned u = 0;
    u = __builtin_amdgcn_cvt_pk_fp8_f32(a, b, u, false);  // bytes 0,1
    u = __builtin_amdgcn_cvt_pk_fp8_f32(c, d, u, true);   // bytes 2,3
    return u;
}

#define GLOAD_LDS16(SRC, DST)                                                  \
    __builtin_amdgcn_global_load_lds(                                          \
        (const __attribute__((address_space(1))) void*)(SRC),                  \
        (__attribute__((address_space(3))) void*)(DST), 16, 0, 0)

// ---- weight prep: pre-swizzled fp8 B images + coords + alpha ----
// Image[t=nb*9+tap][row 0..127][ch 0..7] (16B chunks):
//   fp8 of w[k = tap*128 + (ch^(row&7))*16 + j][n = nb*128 + row], j=0..15
__global__ void wprep_kernel(const float* __restrict__ w,
                             const float* __restrict__ alpha,
                             unsigned char* __restrict__ Bw,
                             float* __restrict__ out) {
    int cid = blockIdx.x * 256 + threadIdx.x;     // 0..36863
    if (cid < 32768) {                            // coords
        int b = cid >> 12, iy = (cid >> 6) & 63, ix = cid & 63;
        float* c = out + OUT_COORDS_OFF + (size_t)cid * 3;
        c[0] = (float)b; c[1] = (float)iy; c[2] = (float)ix;
        if (cid == 0) out[ALPHA_OFF] = alpha[0];
    }
    if (cid < 18432) {                            // 18 images x 128 rows x 8 chunks
        int ch  = cid & 7;
        int row = (cid >> 3) & 127;
        int t   = cid >> 10;                      // 0..17 = nb*9 + tap
        int nb  = (t >= 9) ? 1 : 0;
        int tap = t - 9 * nb;
        int chp = ch ^ (row & 7);
        int n   = (nb << 7) + row;
        int kb  = (tap << 7) + (chp << 4);
        unsigned u[4];
#pragma unroll
        for (int q = 0; q < 4; ++q) {
            float f0 = w[(size_t)(kb + 4 * q + 0) * 256 + n];
            float f1 = w[(size_t)(kb + 4 * q + 1) * 256 + n];
            float f2 = w[(size_t)(kb + 4 * q + 2) * 256 + n];
            float f3 = w[(size_t)(kb + 4 * q + 3) * 256 + n];
            u[q] = pk4fp8(f0, f1, f2, f3);
        }
        uint4 r; r.x = u[0]; r.y = u[1]; r.z = u[2]; r.w = u[3];
        *(uint4*)(Bw + (size_t)cid * 16) = r;
    }
}

// ---- coords for fallback path ----
__global__ void coords_alpha_kernel(float* __restrict__ out, const float* __restrict__ alpha) {
    int i = blockIdx.x * 256 + threadIdx.x;
    int b = i >> 12, iy = (i >> 6) & 63, ix = i & 63;
    float* c = out + OUT_COORDS_OFF + (size_t)i * 3;
    c[0] = (float)b; c[1] = (float)iy; c[2] = (float)ix;
    if (i == 0) out[ALPHA_OFF] = alpha[0];
}

// ---- fused conv GEMM: persistent LDS A-band (5 input rows, fp8, swizzled),
//      9-tap loop stages only B; fp8 32x32x16 MFMA; counted vmcnt; 16 waves ----
// Aband layout: [r 0..4][nxp 0..129][128B of k-chans], chunk c stored at
//   c ^ ((nxp>>1)&7). nxp = input_nx + 1 (nxp=0 is the nx=-1 zero pad).
// r = ny - (2*iy0 - 1). Row r=0 zeroed when iy0==0 (ny=-1).
__global__ __launch_bounds__(1024, 1) void gemm_conv_kernel(
    const float* __restrict__ feats,         // fp32 [B*128*128][128]
    const unsigned char* __restrict__ Bw,    // pre-swizzled fp8 B images (18 x 16KB)
    float* __restrict__ out)                 // [32768][256]
{
    __shared__ unsigned char Aband[5 * 130 * 128];   // 83,200 B
    __shared__ unsigned char Bs[2][256 * 128];       // 2 x 32,768 B

    const int tid  = threadIdx.x;
    const int bid  = blockIdx.x;             // 0..255
    // XCD-aware: XCD (bid&7) owns batch bb=(bid&7).
    const int my   = ((bid & 7) << 5) + (bid >> 3);
    const int m0   = my << 7;
    const int bb   = my >> 5;                // == bid & 7
    const int iy0  = ((my & 31) << 1);       // 0..62 even

    const int lane = tid & 63, wave = tid >> 6;  // wave 0..15
    const int wm   = (wave >> 2) << 5;       // 0 / 32 / 64 / 96
    const int wn   = (wave & 3) << 6;        // 0 / 64 / 128 / 192
    const int l31  = lane & 31;
    const int hh   = lane >> 5;              // k-half select
    const int xorl = l31 & 7;

    // ---- B staging machinery (2 x global_load_lds per wave per tap) ----
    // wave w stages Bs rows [w*16, w*16+16) from image (w>>3)*9+tap rows (w&7)*16..
    const unsigned char* bsrc0 = Bw + ((size_t)((wave >> 3) * 9) << 14)
                                    + ((size_t)(wave & 7) << 11) + ((size_t)lane << 4);
    auto stageB = [&](int tap, int buf) {
        const unsigned char* bs = bsrc0 + ((size_t)tap << 14);
        unsigned char* bdst = Bs[buf] + (wave << 11);
#pragma unroll
        for (int q = 0; q < 2; ++q)
            GLOAD_LDS16(bs + (q << 10), bdst + (q << 10));
    };

    stageB(0, 0);                             // overlap tap-0 B DMA with band phase

    // ---- phase 0: zero pads ----
    if (tid < 40) {                          // nxp=0 column: 5 rows x 8 chunks
        const int r = tid >> 3, c = tid & 7; // key((0)>>1)=0 -> chunk stored at c
        uint4 z; z.x = 0u; z.y = 0u; z.z = 0u; z.w = 0u;
        *(uint4*)(Aband + ((r * 130) << 7) + (c << 4)) = z;
    }
    if (iy0 == 0) {                          // row r=0 (ny=-1): 130 x 8 chunks
        for (int z = tid; z < 1040; z += 1024) {
            const int nxp = z >> 3, c = z & 7;
            uint4 zz; zz.x = 0u; zz.y = 0u; zz.z = 0u; zz.w = 0u;
            *(uint4*)(Aband + (nxp << 7) + ((c ^ ((nxp >> 1) & 7)) << 4)) = zz;
        }
    }

    // ---- phase 1: load + convert the 5-row fp32 band into LDS ----
    {
        const int ny0 = (iy0 << 1) - 1;
        auto loadBand = [&](int vstart, int iters) {
#pragma unroll 4
            for (int it = 0; it < iters; ++it) {
                const int o   = (tid + (it << 10)) << 4; // byte offset in valid region
                const int r   = vstart + (o >> 16);      // band row
                const int br  = o & 65535;
                const int nx  = br >> 9;
                const int ch0 = (br & 511) >> 2;         // float idx 0..124 step 4
                const float4 f = *(const float4*)(feats +
                    ((((size_t)(bb << 14) + (ny0 + r) * 128 + nx)) << 7) + ch0);
                const unsigned u = pk4fp8(f.x, f.y, f.z, f.w);
                const int c   = ch0 >> 4;
                const int nxp = nx + 1;
                *(unsigned*)(Aband + ((r * 130 + nxp) << 7)
                             + ((c ^ ((nxp >> 1) & 7)) << 4) + (ch0 & 15)) = u;
            }
        };
        if (iy0 == 0) loadBand(1, 16); else loadBand(0, 20);
    }
    __syncthreads();                          // band + tap0 B ordering point (waves)

    v16f acc[2];
#pragma unroll
    for (int j = 0; j < 2; j++) acc[j] = (v16f)(0.0f);

    auto computeTap = [&](int buf, int dy, int dx) {
        const int bandrow = ((wm >> 6) << 1) + dy + 1;   // wave-uniform, 0..4
        const int ixv = (wm & 63) + l31;                 // 0..63
        const int nxp = (ixv << 1) + dx + 1;             // 0..128
        const int abase = ((bandrow * 130 + nxp) << 7) + (hh << 3);
        const int akey  = (nxp >> 1) & 7;
#pragma unroll
        for (int seg = 0; seg < 8; ++seg) {   // K=128 -> 8 x (32x32x16)
            long long a0, b2[2];
            a0 = *(const long long*)(Aband + abase + ((seg ^ akey) << 4));
#pragma unroll
            for (int j = 0; j < 2; j++)
                b2[j] = *(const long long*)(Bs[buf] + ((wn + (j << 5) + l31) << 7)
                                            + ((seg ^ xorl) << 4) + (hh << 3));
            __builtin_amdgcn_s_setprio(1);
#pragma unroll
            for (int j = 0; j < 2; j++)
                acc[j] = __builtin_amdgcn_mfma_f32_32x32x16_fp8_fp8(a0, b2[j], acc[j], 0, 0, 0);
            __builtin_amdgcn_s_setprio(0);
        }
    };

#pragma unroll
    for (int tap = 0; tap < 9; ++tap) {
        if (tap < 8) {
            stageB(tap + 1, (tap + 1) & 1);
            // own 2 oldest (tap's B) drained; next tap's 2 stay in flight.
            asm volatile("s_waitcnt vmcnt(2)\ns_barrier" ::: "memory");
        } else {
            asm volatile("s_waitcnt vmcnt(0)\ns_barrier" ::: "memory");
        }
        computeTap(tap & 1, tap / 3 - 1, tap % 3 - 1);
        if (tap < 8)                          // protect buf reuse by next stage
            asm volatile("s_barrier" ::: "memory");
    }

    // epilogue: 32x32 D layout col=lane&31, row=(reg&3)+8*(reg>>2)+4*(lane>>5)  [m74/m101]
    // nt stores: output stream does not allocate/thrash L2.
#pragma unroll
    for (int j = 0; j < 2; j++) {
        const int gcol = wn + (j << 5) + l31;
#pragma unroll
        for (int r = 0; r < 16; ++r) {
            const int grow = m0 + wm + (r & 3) + ((r >> 2) << 3) + (hh << 2);
            __builtin_nontemporal_store(acc[j][r], &out[(size_t)grow * 256 + gcol]);
        }
    }
}

// ---- fallback: direct fp32 conv ----
__global__ void naive_conv_kernel(const float* __restrict__ feats,
                                  const float* __restrict__ w,
                                  float* __restrict__ out) {
    int m = blockIdx.x;
    int n = threadIdx.x;
    int bb = m >> 12, iy = (m >> 6) & 63, ix = m & 63;
    float acc = 0.f;
    for (int tap = 0; tap < 9; ++tap) {
        int ny = 2 * iy + tap / 3 - 1;
        int nx = 2 * ix + tap % 3 - 1;
        if ((unsigned)ny < 128u && (unsigned)nx < 128u) {
            const float* fr = feats + ((size_t)((bb << 14) + (ny << 7) + nx) << 7);
            const float* wr = w + tap * 32768 + n;
            for (int c = 0; c < 128; ++c) acc += fr[c] * wr[c * 256];
        }
    }
    out[(size_t)m * 256 + n] = acc;
}

extern "C" void kernel_launch(void* const* d_in, const int* in_sizes, int n_in,
                              void* d_out, int out_size, void* d_ws, size_t ws_size,
                              hipStream_t stream) {
    const float* feats  = (const float*)d_in[0];
    const float* weight = (const float*)d_in[1];
    const float* alpha  = (const float*)d_in[2];
    float* out = (float*)d_out;

    const size_t NEED = (size_t)BW_BYTES;
    if (ws_size >= NEED) {
        unsigned char* Bw = (unsigned char*)d_ws;
        wprep_kernel<<<144, 256, 0, stream>>>(weight, alpha, Bw, out);
        gemm_conv_kernel<<<256, 1024, 0, stream>>>(feats, Bw, out);
    } else {
        coords_alpha_kernel<<<128, 256, 0, stream>>>(out, alpha);
        naive_conv_kernel<<<32768, 256, 0, stream>>>(feats, weight, out);
    }
}